// Round 6
// baseline (382.853 us; speedup 1.0000x reference)
//
#include <hip/hip_runtime.h>

#define NN 100000
#define BW 256                       // bucket width in nodes (c >> 8)
#define NB ((NN + BW - 1) / BW)      // 391 buckets
#define CH 4096                      // edges per sort block

typedef __attribute__((ext_vector_type(8))) short short8;
typedef __attribute__((ext_vector_type(4))) float f32x4;

// ---------- bf16 helpers ----------
__device__ __forceinline__ float bf2f(unsigned short u) {
    union { unsigned int i; float f; } v;
    v.i = ((unsigned int)u) << 16;
    return v.f;
}
__device__ __forceinline__ unsigned short f2bf(float f) {
    unsigned int u = __float_as_uint(f);
    unsigned int r = u + 0x7fffu + ((u >> 16) & 1u);  // RNE
    return (unsigned short)(r >> 16);
}
// flags[0]=1 -> float tensors are bf16, else fp32
__device__ __forceinline__ float ldf(const void* p, int i, int bf) {
    return bf ? bf2f(((const unsigned short*)p)[i]) : ((const float*)p)[i];
}
// flags[1]=1 -> edge_index is int64, else int32
__device__ __forceinline__ int lde(const void* p, int i, int i64f) {
    return i64f ? (int)((const long long*)p)[i] : ((const int*)p)[i];
}
// load 8 consecutive float-typed input elements as bf16 short8 (flag-driven)
__device__ __forceinline__ short8 ld8bf(const void* p, size_t i, int bf) {
    if (bf) return *(const short8*)((const unsigned short*)p + i);
    const float* f = (const float*)p + i;
    f32x4 a = *(const f32x4*)f;
    f32x4 b = *(const f32x4*)(f + 4);
    short8 o;
    o[0] = (short)f2bf(a[0]); o[1] = (short)f2bf(a[1]);
    o[2] = (short)f2bf(a[2]); o[3] = (short)f2bf(a[3]);
    o[4] = (short)f2bf(b[0]); o[5] = (short)f2bf(b[1]);
    o[6] = (short)f2bf(b[2]); o[7] = (short)f2bf(b[3]);
    return o;
}

// ---------- dtype detection (parallel, 1 block) ----------
__global__ void detect_kernel(const unsigned int* __restrict__ xw,
                              const unsigned int* __restrict__ eiw,
                              int* __restrict__ flags) {
    __shared__ int s0, s1;
    int tid = threadIdx.x;
    if (tid == 0) { s0 = 0; s1 = 0; }
    __syncthreads();
    if (tid < 128) {
        unsigned int w = xw[tid];
        int e = (int)((w >> 7) & 0xFFu);
        if (e < 100 || e > 130) atomicAdd(&s0, 1);
    } else if (tid < 192) {
        if (eiw[2 * (tid - 128) + 1] == 0u) atomicAdd(&s1, 1);
    }
    __syncthreads();
    if (tid == 0) {
        flags[0] = (s0 < 16) ? 1 : 0;
        flags[1] = (s1 >= 48) ? 1 : 0;
    }
}

// ---------- fused: block-local bucket sort of edges + weight transpose ----------
__global__ __launch_bounds__(512) void sort_tr_kernel(const void* __restrict__ ei, int E,
                                                      int* __restrict__ bcnt,
                                                      int* __restrict__ poff,
                                                      int* __restrict__ ebin,
                                                      const int* __restrict__ flags,
                                                      const void* __restrict__ w1,
                                                      const void* __restrict__ w2,
                                                      unsigned short* __restrict__ w1t,
                                                      unsigned short* __restrict__ w2t,
                                                      int PB) {
    __shared__ int lc[NB + 1];
    __shared__ int ls[512];
    __shared__ int sbuf[CH];
    int bid = blockIdx.x, tid = threadIdx.x;
    if (bid < PB) {
        int i64f = flags[1];
        int base = bid * CH;
        int cntE = min(CH, E - base);
        int re[CH / 512], ce[CH / 512];
        for (int i = tid; i < NB; i += 512) lc[i] = 0;
        __syncthreads();
#pragma unroll
        for (int q = 0; q < CH / 512; ++q) {
            int e = base + q * 512 + tid;
            if (e < E) {
                int r = lde(ei, e, i64f);
                int c = lde(ei, E + e, i64f);
                r = min(max(r, 0), NN - 1);
                c = min(max(c, 0), NN - 1);
                re[q] = r; ce[q] = c;
                atomicAdd(&lc[c >> 8], 1);
            } else {
                re[q] = -1; ce[q] = 0;
            }
        }
        __syncthreads();
        int v = (tid < NB) ? lc[tid] : 0;
        ls[tid] = v;
        __syncthreads();
        for (int o = 1; o < 512; o <<= 1) {
            int t = (tid >= o) ? ls[tid - o] : 0;
            __syncthreads();
            ls[tid] += t;
            __syncthreads();
        }
        int excl = ls[tid] - v;
        if (tid < NB) {
            poff[bid * (NB + 1) + tid] = excl;
            if (v) atomicAdd(&bcnt[tid], v);
        }
        if (tid == 0) poff[bid * (NB + 1) + NB] = cntE;
        __syncthreads();
        if (tid < NB) lc[tid] = excl;  // cursor
        __syncthreads();
#pragma unroll
        for (int q = 0; q < CH / 512; ++q) {
            if (re[q] >= 0) {
                int pos = atomicAdd(&lc[ce[q] >> 8], 1);
                sbuf[pos] = (re[q] << 8) | (ce[q] & 255);
            }
        }
        __syncthreads();
        for (int i = tid; i < cntE; i += 512)
            ebin[base + i] = sbuf[i];
    } else {
        int bf = flags[0];
        int i = (bid - PB) * 512 + tid;
        if (i < 128 * 256) {
            int n = i >> 8, k = i & 255;
            w1t[n * 256 + k] = f2bf(ldf(w1, k * 128 + n, bf));
        } else if (i < 128 * 256 + 64 * 128) {
            int j = i - 128 * 256;
            int n = j >> 7, k = j & 127;
            w2t[n * 128 + k] = f2bf(ldf(w2, k * 64 + n, bf));
        }
    }
}

// ---------- bucket prefix scan (1 block of 512) ----------
__global__ void bscan_kernel(const int* __restrict__ bcnt, int* __restrict__ bstart,
                             int* __restrict__ off, int E) {
    __shared__ int s[512];
    int tid = threadIdx.x;
    int v = (tid < NB) ? bcnt[tid] : 0;
    s[tid] = v;
    __syncthreads();
    for (int o = 1; o < 512; o <<= 1) {
        int t = (tid >= o) ? s[tid - o] : 0;
        __syncthreads();
        s[tid] += t;
        __syncthreads();
    }
    int excl = s[tid] - v;
    if (tid < NB) bstart[tid] = excl;
    if (tid == NB - 1) bstart[NB] = excl + v;  // == E
    if (tid == 0) off[NN] = E;
}

// ---------- per-bucket CSR build (standalone, latency regime) ----------
// wave-per-sort-block, lanes stride the segment -> parallel gather
__global__ __launch_bounds__(512) void csr_kernel(const int* __restrict__ ebin,
                                                  const int* __restrict__ poff,
                                                  const int* __restrict__ bstart,
                                                  int* __restrict__ off,
                                                  float* __restrict__ dinv,
                                                  int* __restrict__ epair, int PB) {
    __shared__ int cnt[BW], pfx[BW];
    int b = blockIdx.x, tid = threadIdx.x;
    int lane = tid & 63, wv = tid >> 6;  // 8 waves
    int c0 = b << 8;
    int s = bstart[b];
    for (int i = tid; i < BW; i += 512) cnt[i] = 0;
    __syncthreads();
    for (int p = wv; p < PB; p += 8) {
        const int* pr = poff + p * (NB + 1);
        int s0 = p * CH + pr[b], s1 = p * CH + pr[b + 1];
        for (int i = s0 + lane; i < s1; i += 64)
            atomicAdd(&cnt[ebin[i] & 255], 1);
    }
    __syncthreads();
    int v = (tid < BW) ? cnt[tid] : 0;
    if (tid < BW) pfx[tid] = v;
    __syncthreads();
    for (int o = 1; o < BW; o <<= 1) {
        int t = (tid < BW && tid >= o) ? pfx[tid - o] : 0;
        __syncthreads();
        if (tid < BW) pfx[tid] += t;
        __syncthreads();
    }
    if (tid < BW) {
        int basec = s + pfx[tid] - v;   // exclusive prefix -> global CSR offset
        int node = c0 + tid;
        if (node < NN) {
            off[node] = basec;
            dinv[node] = rsqrtf((float)(v + 1));  // +1 self loop
        }
        cnt[tid] = basec;  // becomes cursor
    }
    __syncthreads();
    for (int p = wv; p < PB; p += 8) {
        const int* pr = poff + p * (NB + 1);
        int s0 = p * CH + pr[b], s1 = p * CH + pr[b + 1];
        for (int i = s0 + lane; i < s1; i += 64) {
            int w = ebin[i];
            int pos = atomicAdd(&cnt[w & 255], 1);
            epair[pos] = w >> 8;
        }
    }
}

// ---------- GEMM1 standalone (512 thr, 128 rows/block, x prefetched) ----------
__global__ __launch_bounds__(512) void gemm1_kernel(const int* __restrict__ flags,
                                                    const void* __restrict__ x,
                                                    const unsigned short* __restrict__ wt,
                                                    unsigned short* __restrict__ h) {
    __shared__ unsigned short wl[128 * 136];  // 34.8 KB
    int tid = threadIdx.x;
    int bf = flags[0];
    int lane = tid & 63, wv = tid >> 6;       // 0..7
    int ln = lane & 15, kq = lane >> 4;
    int rowBase = blockIdx.x * 128 + wv * 16;
    int anode = min(rowBase + ln, NN - 1);
    size_t abase = (size_t)anode * 256;
    // prefetch half-0 A fragments (hides HBM latency under staging)
    short8 a0[4];
#pragma unroll
    for (int q = 0; q < 4; ++q)
        a0[q] = ld8bf(x, abase + q * 32 + kq * 8, bf);
    f32x4 acc[8];
#pragma unroll
    for (int t = 0; t < 8; ++t) acc[t] = (f32x4)0.f;

    // ---- half 0 ----
    __syncthreads();
    for (int i = tid; i < 128 * 16; i += 512) {
        int n = i >> 4, b = i & 15;
        short8 v = *(const short8*)(wt + n * 256 + b * 8);
        *(short8*)(&wl[n * 136 + b * 8]) = v;
    }
    __syncthreads();
    // prefetch half-1 A fragments (overlaps with half-0 MFMA)
    short8 a1[4];
#pragma unroll
    for (int q = 0; q < 4; ++q)
        a1[q] = ld8bf(x, abase + 128 + q * 32 + kq * 8, bf);
#pragma unroll
    for (int ks = 0; ks < 4; ++ks) {
        int klocal = ks * 32 + kq * 8;
#pragma unroll
        for (int t = 0; t < 8; ++t) {
            int n = t * 16 + ln;
            short8 b = *(const short8*)(&wl[n * 136 + klocal]);
            acc[t] = __builtin_amdgcn_mfma_f32_16x16x32_bf16(a0[ks], b, acc[t], 0, 0, 0);
        }
    }
    // ---- half 1 ----
    __syncthreads();
    for (int i = tid; i < 128 * 16; i += 512) {
        int n = i >> 4, b = i & 15;
        short8 v = *(const short8*)(wt + n * 256 + 128 + b * 8);
        *(short8*)(&wl[n * 136 + b * 8]) = v;
    }
    __syncthreads();
#pragma unroll
    for (int ks = 0; ks < 4; ++ks) {
        int klocal = ks * 32 + kq * 8;
#pragma unroll
        for (int t = 0; t < 8; ++t) {
            int n = t * 16 + ln;
            short8 b = *(const short8*)(&wl[n * 136 + klocal]);
            acc[t] = __builtin_amdgcn_mfma_f32_16x16x32_bf16(a1[ks], b, acc[t], 0, 0, 0);
        }
    }
#pragma unroll
    for (int r = 0; r < 4; ++r) {
        int node = rowBase + kq * 4 + r;
        if (node < NN) {
            unsigned short* orow = h + (size_t)node * 128;
#pragma unroll
            for (int t = 0; t < 8; ++t)
                orow[t * 16 + ln] = f2bf(acc[t][r]);
        }
    }
}

// ---------- agg layer1: 4 dests/wave, group-per-dest, unroll-4 batched gather ----------
__global__ __launch_bounds__(256) void agg1_kernel(const unsigned short* __restrict__ h,
                                                   const float* __restrict__ dinv,
                                                   const int* __restrict__ off,
                                                   const int* __restrict__ epair,
                                                   const void* __restrict__ b1,
                                                   unsigned short* __restrict__ outp,
                                                   const int* __restrict__ flags) {
    int tid = threadIdx.x;
    int lane = tid & 63, wv = tid >> 6;
    int g = lane >> 4, l = lane & 15;   // group = dest, 16 feature-lanes
    int c = blockIdx.x * 16 + wv * 4 + g;
    if (c >= NN) return;
    int bf = flags[0];
    float dc = dinv[c];
    int jb = off[c], je = off[c + 1];
    float acc[8];
    {
        short8 v = *(const short8*)(h + (size_t)c * 128 + l * 8);
        float w = dc * dc;
#pragma unroll
        for (int f = 0; f < 8; ++f) acc[f] = bf2f((unsigned short)v[f]) * w;
    }
    int j = jb;
    for (; j + 3 < je; j += 4) {
        int s0 = epair[j], s1 = epair[j + 1], s2 = epair[j + 2], s3 = epair[j + 3];
        float w0 = dinv[s0] * dc, w1 = dinv[s1] * dc;
        float w2 = dinv[s2] * dc, w3 = dinv[s3] * dc;
        short8 v0 = *(const short8*)(h + (size_t)s0 * 128 + l * 8);
        short8 v1 = *(const short8*)(h + (size_t)s1 * 128 + l * 8);
        short8 v2 = *(const short8*)(h + (size_t)s2 * 128 + l * 8);
        short8 v3 = *(const short8*)(h + (size_t)s3 * 128 + l * 8);
#pragma unroll
        for (int f = 0; f < 8; ++f) {
            acc[f] = fmaf(bf2f((unsigned short)v0[f]), w0, acc[f]);
            acc[f] = fmaf(bf2f((unsigned short)v1[f]), w1, acc[f]);
            acc[f] = fmaf(bf2f((unsigned short)v2[f]), w2, acc[f]);
            acc[f] = fmaf(bf2f((unsigned short)v3[f]), w3, acc[f]);
        }
    }
    for (; j < je; ++j) {
        int s0 = epair[j];
        float w = dinv[s0] * dc;
        short8 v = *(const short8*)(h + (size_t)s0 * 128 + l * 8);
#pragma unroll
        for (int f = 0; f < 8; ++f) acc[f] = fmaf(bf2f((unsigned short)v[f]), w, acc[f]);
    }
    short8 o;
#pragma unroll
    for (int f = 0; f < 8; ++f)
        o[f] = (short)f2bf(fmaxf(acc[f] + ldf(b1, l * 8 + f, bf), 0.f));
    *(short8*)(outp + (size_t)c * 128 + l * 8) = o;
}

// ---------- GEMM2 (512 thr, 128 rows/block): h2[N,64](bf16) = agg1[N,128] @ W2 ----------
__global__ __launch_bounds__(512) void gemm2_kernel(const unsigned short* __restrict__ a_,
                                                    const unsigned short* __restrict__ wt,
                                                    unsigned short* __restrict__ h2) {
    __shared__ unsigned short wl[64 * 136];  // ~17 KB
    int tid = threadIdx.x;
    for (int i = tid; i < 64 * 16; i += 512) {
        int n = i >> 4, b = i & 15;
        short8 v = *(const short8*)(wt + n * 128 + b * 8);
        *(short8*)(&wl[n * 136 + b * 8]) = v;
    }
    __syncthreads();
    int lane = tid & 63, wv = tid >> 6;       // 0..7
    int ln = lane & 15, kq = lane >> 4;
    int rowBase = blockIdx.x * 128 + wv * 16;
    int anode = min(rowBase + ln, NN - 1);
    const unsigned short* arow = a_ + (size_t)anode * 128;
    f32x4 acc[4];
#pragma unroll
    for (int t = 0; t < 4; ++t) acc[t] = (f32x4)0.f;
#pragma unroll
    for (int ks = 0; ks < 4; ++ks) {
        int k0 = ks * 32 + kq * 8;
        short8 a = *(const short8*)(arow + k0);
#pragma unroll
        for (int t = 0; t < 4; ++t) {
            int n = t * 16 + ln;
            short8 b = *(const short8*)(&wl[n * 136 + k0]);
            acc[t] = __builtin_amdgcn_mfma_f32_16x16x32_bf16(a, b, acc[t], 0, 0, 0);
        }
    }
#pragma unroll
    for (int r = 0; r < 4; ++r) {
        int node = rowBase + kq * 4 + r;
        if (node < NN) {
            unsigned short* orow = h2 + (size_t)node * 64;
#pragma unroll
            for (int t = 0; t < 4; ++t)
                orow[t * 16 + ln] = f2bf(acc[t][r]);
        }
    }
}

// ---------- agg layer2: 8 dests/wave, group-per-dest, unroll-4 batched gather ----------
__global__ __launch_bounds__(256) void agg_out_kernel(const unsigned short* __restrict__ h,
                                                      const float* __restrict__ dinv,
                                                      const int* __restrict__ off,
                                                      const int* __restrict__ epair,
                                                      const void* __restrict__ b2,
                                                      void* __restrict__ outp,
                                                      const int* __restrict__ flags) {
    int tid = threadIdx.x;
    int lane = tid & 63, wv = tid >> 6;
    int g = lane >> 3, l = lane & 7;   // group = dest, 8 feature-lanes
    int c = blockIdx.x * 32 + wv * 8 + g;
    if (c >= NN) return;
    int bf = flags[0];
    float dc = dinv[c];
    int jb = off[c], je = off[c + 1];
    float acc[8];
    {
        short8 v = *(const short8*)(h + (size_t)c * 64 + l * 8);
        float w = dc * dc;
#pragma unroll
        for (int f = 0; f < 8; ++f) acc[f] = bf2f((unsigned short)v[f]) * w;
    }
    int j = jb;
    for (; j + 3 < je; j += 4) {
        int s0 = epair[j], s1 = epair[j + 1], s2 = epair[j + 2], s3 = epair[j + 3];
        float w0 = dinv[s0] * dc, w1 = dinv[s1] * dc;
        float w2 = dinv[s2] * dc, w3 = dinv[s3] * dc;
        short8 v0 = *(const short8*)(h + (size_t)s0 * 64 + l * 8);
        short8 v1 = *(const short8*)(h + (size_t)s1 * 64 + l * 8);
        short8 v2 = *(const short8*)(h + (size_t)s2 * 64 + l * 8);
        short8 v3 = *(const short8*)(h + (size_t)s3 * 64 + l * 8);
#pragma unroll
        for (int f = 0; f < 8; ++f) {
            acc[f] = fmaf(bf2f((unsigned short)v0[f]), w0, acc[f]);
            acc[f] = fmaf(bf2f((unsigned short)v1[f]), w1, acc[f]);
            acc[f] = fmaf(bf2f((unsigned short)v2[f]), w2, acc[f]);
            acc[f] = fmaf(bf2f((unsigned short)v3[f]), w3, acc[f]);
        }
    }
    for (; j < je; ++j) {
        int s0 = epair[j];
        float w = dinv[s0] * dc;
        short8 v = *(const short8*)(h + (size_t)s0 * 64 + l * 8);
#pragma unroll
        for (int f = 0; f < 8; ++f) acc[f] = fmaf(bf2f((unsigned short)v[f]), w, acc[f]);
    }
    if (bf) {
        short8 o;
#pragma unroll
        for (int f = 0; f < 8; ++f)
            o[f] = (short)f2bf(acc[f] + ldf(b2, l * 8 + f, 1));
        *(short8*)((unsigned short*)outp + (size_t)c * 64 + l * 8) = o;
    } else {
        float* op = (float*)outp + (size_t)c * 64 + l * 8;
#pragma unroll
        for (int f = 0; f < 8; ++f)
            op[f] = acc[f] + ldf(b2, l * 8 + f, 0);
    }
}

extern "C" void kernel_launch(void* const* d_in, const int* in_sizes, int n_in,
                              void* d_out, int out_size, void* d_ws, size_t ws_size,
                              hipStream_t stream) {
    const void* x  = d_in[0];
    const void* ei = d_in[1];
    const void* W1 = d_in[2];
    const void* b1 = d_in[3];
    const void* W2 = d_in[4];
    const void* b2 = d_in[5];

    const int N = NN;
    const int E = in_sizes[1] / 2;
    const int PB = (E + CH - 1) / CH;                  // sort blocks
    const int GB = (N + 127) / 128;                    // gemm blocks (128 rows each)
    const int TB = (128 * 256 + 64 * 128 + 511) / 512; // transpose blocks

    char* ws = (char*)d_ws;
    size_t o = 0;
    auto alloc = [&](size_t bytes) { size_t r = o; o += (bytes + 255) & ~(size_t)255; return r; };
    int*   flags  = (int*)(ws + alloc(256));
    int*   bcnt   = (int*)(ws + alloc((size_t)(NB + 1) * 4));
    int*   bstart = (int*)(ws + alloc((size_t)(NB + 1) * 4));
    int*   off    = (int*)(ws + alloc((size_t)(N + 1) * 4));
    float* dinv   = (float*)(ws + alloc((size_t)N * 4));
    int*   epair  = (int*)(ws + alloc((size_t)E * 4));
    int*   poff   = (int*)(ws + alloc((size_t)PB * (NB + 1) * 4));
    unsigned short* w1t  = (unsigned short*)(ws + alloc(128 * 256 * 2));
    unsigned short* w2t  = (unsigned short*)(ws + alloc(64 * 128 * 2));
    unsigned short* h1   = (unsigned short*)(ws + alloc((size_t)N * 128 * 2));
    unsigned short* agg1 = (unsigned short*)(ws + alloc((size_t)N * 128 * 2));
    unsigned short* h2   = h1;          // reuse (h1 dead after agg1_kernel)
    int* ebin = (int*)agg1;             // staging reuse: E*4 <= N*256 bytes

    detect_kernel<<<1, 256, 0, stream>>>((const unsigned int*)x, (const unsigned int*)ei, flags);
    hipMemsetAsync(bcnt, 0, (size_t)(NB + 1) * 4, stream);
    sort_tr_kernel<<<PB + TB, 512, 0, stream>>>(ei, E, bcnt, poff, ebin, flags, W1, W2, w1t, w2t, PB);
    bscan_kernel<<<1, 512, 0, stream>>>(bcnt, bstart, off, E);
    csr_kernel<<<NB, 512, 0, stream>>>(ebin, poff, bstart, off, dinv, epair, PB);
    gemm1_kernel<<<GB, 512, 0, stream>>>(flags, x, w1t, h1);
    agg1_kernel<<<(N + 15) / 16, 256, 0, stream>>>(h1, dinv, off, epair, b1, agg1, flags);
    gemm2_kernel<<<GB, 512, 0, stream>>>(agg1, w2t, h2);
    agg_out_kernel<<<(N + 31) / 32, 256, 0, stream>>>(h2, dinv, off, epair, b2, d_out, flags);
}

// Round 7
// 341.913 us; speedup vs baseline: 1.1197x; 1.1197x over previous
//
#include <hip/hip_runtime.h>

#define NN 100000
#define BW 256                       // bucket width in nodes (c >> 8)
#define NB ((NN + BW - 1) / BW)      // 391 buckets
#define CH 4096                      // edges per sort block

typedef __attribute__((ext_vector_type(8))) short short8;
typedef __attribute__((ext_vector_type(4))) float f32x4;

// ---------- bf16 helpers ----------
__device__ __forceinline__ float bf2f(unsigned short u) {
    union { unsigned int i; float f; } v;
    v.i = ((unsigned int)u) << 16;
    return v.f;
}
__device__ __forceinline__ unsigned short f2bf(float f) {
    unsigned int u = __float_as_uint(f);
    unsigned int r = u + 0x7fffu + ((u >> 16) & 1u);  // RNE
    return (unsigned short)(r >> 16);
}
// flags[0]=1 -> float tensors are bf16, else fp32
__device__ __forceinline__ float ldf(const void* p, int i, int bf) {
    return bf ? bf2f(((const unsigned short*)p)[i]) : ((const float*)p)[i];
}
// flags[1]=1 -> edge_index is int64, else int32
__device__ __forceinline__ int lde(const void* p, int i, int i64f) {
    return i64f ? (int)((const long long*)p)[i] : ((const int*)p)[i];
}
// load 8 consecutive float-typed input elements as bf16 short8 (flag-driven)
__device__ __forceinline__ short8 ld8bf(const void* p, size_t i, int bf) {
    if (bf) return *(const short8*)((const unsigned short*)p + i);
    const float* f = (const float*)p + i;
    f32x4 a = *(const f32x4*)f;
    f32x4 b = *(const f32x4*)(f + 4);
    short8 o;
    o[0] = (short)f2bf(a[0]); o[1] = (short)f2bf(a[1]);
    o[2] = (short)f2bf(a[2]); o[3] = (short)f2bf(a[3]);
    o[4] = (short)f2bf(b[0]); o[5] = (short)f2bf(b[1]);
    o[6] = (short)f2bf(b[2]); o[7] = (short)f2bf(b[3]);
    return o;
}

// ---------- dtype detection (parallel, 1 block) ----------
__global__ void detect_kernel(const unsigned int* __restrict__ xw,
                              const unsigned int* __restrict__ eiw,
                              int* __restrict__ flags) {
    __shared__ int s0, s1;
    int tid = threadIdx.x;
    if (tid == 0) { s0 = 0; s1 = 0; }
    __syncthreads();
    if (tid < 128) {
        unsigned int w = xw[tid];
        int e = (int)((w >> 7) & 0xFFu);
        if (e < 100 || e > 130) atomicAdd(&s0, 1);
    } else if (tid < 192) {
        if (eiw[2 * (tid - 128) + 1] == 0u) atomicAdd(&s1, 1);
    }
    __syncthreads();
    if (tid == 0) {
        flags[0] = (s0 < 16) ? 1 : 0;
        flags[1] = (s1 >= 48) ? 1 : 0;
    }
}

// ---------- fused: block-local bucket sort of edges + weight transpose ----------
__global__ __launch_bounds__(512) void sort_tr_kernel(const void* __restrict__ ei, int E,
                                                      int* __restrict__ bcnt,
                                                      int* __restrict__ poff,
                                                      int* __restrict__ ebin,
                                                      const int* __restrict__ flags,
                                                      const void* __restrict__ w1,
                                                      const void* __restrict__ w2,
                                                      unsigned short* __restrict__ w1t,
                                                      unsigned short* __restrict__ w2t,
                                                      int PB) {
    __shared__ int lc[NB + 1];
    __shared__ int ls[512];
    __shared__ int sbuf[CH];
    int bid = blockIdx.x, tid = threadIdx.x;
    if (bid < PB) {
        int i64f = flags[1];
        int base = bid * CH;
        int cntE = min(CH, E - base);
        int re[CH / 512], ce[CH / 512];
        for (int i = tid; i < NB; i += 512) lc[i] = 0;
        __syncthreads();
#pragma unroll
        for (int q = 0; q < CH / 512; ++q) {
            int e = base + q * 512 + tid;
            if (e < E) {
                int r = lde(ei, e, i64f);
                int c = lde(ei, E + e, i64f);
                r = min(max(r, 0), NN - 1);
                c = min(max(c, 0), NN - 1);
                re[q] = r; ce[q] = c;
                atomicAdd(&lc[c >> 8], 1);
            } else {
                re[q] = -1; ce[q] = 0;
            }
        }
        __syncthreads();
        int v = (tid < NB) ? lc[tid] : 0;
        ls[tid] = v;
        __syncthreads();
        for (int o = 1; o < 512; o <<= 1) {
            int t = (tid >= o) ? ls[tid - o] : 0;
            __syncthreads();
            ls[tid] += t;
            __syncthreads();
        }
        int excl = ls[tid] - v;
        if (tid < NB) {
            poff[bid * (NB + 1) + tid] = excl;
            if (v) atomicAdd(&bcnt[tid], v);
        }
        if (tid == 0) poff[bid * (NB + 1) + NB] = cntE;
        __syncthreads();
        if (tid < NB) lc[tid] = excl;  // cursor
        __syncthreads();
#pragma unroll
        for (int q = 0; q < CH / 512; ++q) {
            if (re[q] >= 0) {
                int pos = atomicAdd(&lc[ce[q] >> 8], 1);
                sbuf[pos] = (re[q] << 8) | (ce[q] & 255);
            }
        }
        __syncthreads();
        for (int i = tid; i < cntE; i += 512)
            ebin[base + i] = sbuf[i];
    } else {
        int bf = flags[0];
        int i = (bid - PB) * 512 + tid;
        if (i < 128 * 256) {
            int n = i >> 8, k = i & 255;
            w1t[n * 256 + k] = f2bf(ldf(w1, k * 128 + n, bf));
        } else if (i < 128 * 256 + 64 * 128) {
            int j = i - 128 * 256;
            int n = j >> 7, k = j & 127;
            w2t[n * 128 + k] = f2bf(ldf(w2, k * 64 + n, bf));
        }
    }
}

// ---------- bucket prefix scan (1 block of 512) ----------
__global__ void bscan_kernel(const int* __restrict__ bcnt, int* __restrict__ bstart,
                             int* __restrict__ off, int E) {
    __shared__ int s[512];
    int tid = threadIdx.x;
    int v = (tid < NB) ? bcnt[tid] : 0;
    s[tid] = v;
    __syncthreads();
    for (int o = 1; o < 512; o <<= 1) {
        int t = (tid >= o) ? s[tid - o] : 0;
        __syncthreads();
        s[tid] += t;
        __syncthreads();
    }
    int excl = s[tid] - v;
    if (tid < NB) bstart[tid] = excl;
    if (tid == NB - 1) bstart[NB] = excl + v;  // == E
    if (tid == 0) off[NN] = E;
}

// ---------- fused: per-bucket CSR build (L2-local) + GEMM1 (512 thr, 128 rows/block) ----------
__global__ __launch_bounds__(512) void sg1_kernel(const int* __restrict__ ebin,
                                                  const int* __restrict__ poff,
                                                  const int* __restrict__ bstart,
                                                  int* __restrict__ off,
                                                  float* __restrict__ dinv,
                                                  int* __restrict__ epair,
                                                  const int* __restrict__ flags,
                                                  const void* __restrict__ x,
                                                  const unsigned short* __restrict__ wt,
                                                  unsigned short* __restrict__ h,
                                                  int GB, int PB) {
    __shared__ unsigned short wl[128 * 136];  // 34.8 KB (gemm path)
    __shared__ int cnt[BW], pfx[BW];          // csr path
    int bid = blockIdx.x, tid = threadIdx.x;
    bool isC = ((bid % 3) == 0) && (bid / 3 < NB);
    if (isC) {
        // -------- CSR path: bucket b, gather segments from each sort block --------
        int b = bid / 3;
        int c0 = b << 8;
        int s = bstart[b];
        for (int i = tid; i < BW; i += 512) cnt[i] = 0;
        __syncthreads();
        for (int p = tid; p < PB; p += 512) {
            const int* pr = poff + p * (NB + 1);
            int s0 = p * CH + pr[b], s1 = p * CH + pr[b + 1];
            for (int i = s0; i < s1; ++i)
                atomicAdd(&cnt[ebin[i] & 255], 1);
        }
        __syncthreads();
        int v = (tid < BW) ? cnt[tid] : 0;
        if (tid < BW) pfx[tid] = v;
        __syncthreads();
        for (int o = 1; o < BW; o <<= 1) {
            int t = (tid < BW && tid >= o) ? pfx[tid - o] : 0;
            __syncthreads();
            if (tid < BW) pfx[tid] += t;
            __syncthreads();
        }
        if (tid < BW) {
            int basec = s + pfx[tid] - v;   // exclusive prefix -> global CSR offset
            int node = c0 + tid;
            if (node < NN) {
                off[node] = basec;
                dinv[node] = rsqrtf((float)(v + 1));  // +1 self loop
            }
            cnt[tid] = basec;  // becomes cursor
        }
        __syncthreads();
        for (int p = tid; p < PB; p += 512) {
            const int* pr = poff + p * (NB + 1);
            int s0 = p * CH + pr[b], s1 = p * CH + pr[b + 1];
            for (int i = s0; i < s1; ++i) {
                int w = ebin[i];
                int pos = atomicAdd(&cnt[w & 255], 1);
                epair[pos] = w >> 8;
            }
        }
        return;
    }
    // -------- gemm1 path: 8 waves x 16 rows = 128 rows/block, W1 staged in LDS --------
    int gb = bid - min(bid / 3 + 1, NB);
    int bf = flags[0];
    int lane = tid & 63, wv = tid >> 6;       // wv in 0..7
    int ln = lane & 15, kq = lane >> 4;
    int rowBase = gb * 128 + wv * 16;
    int anode = min(rowBase + ln, NN - 1);
    size_t abase = (size_t)anode * 256;
    f32x4 acc[8];
#pragma unroll
    for (int t = 0; t < 8; ++t) acc[t] = (f32x4)0.f;

    for (int half = 0; half < 2; ++half) {
        __syncthreads();
        for (int i = tid; i < 128 * 16; i += 512) {
            int n = i >> 4, b = i & 15;
            short8 v = *(const short8*)(wt + n * 256 + half * 128 + b * 8);
            *(short8*)(&wl[n * 136 + b * 8]) = v;
        }
        __syncthreads();
#pragma unroll
        for (int ks = 0; ks < 4; ++ks) {
            int klocal = ks * 32 + kq * 8;
            short8 a = ld8bf(x, abase + half * 128 + klocal, bf);
#pragma unroll
            for (int t = 0; t < 8; ++t) {
                int n = t * 16 + ln;
                short8 b = *(const short8*)(&wl[n * 136 + klocal]);
                acc[t] = __builtin_amdgcn_mfma_f32_16x16x32_bf16(a, b, acc[t], 0, 0, 0);
            }
        }
    }
#pragma unroll
    for (int r = 0; r < 4; ++r) {
        int node = rowBase + kq * 4 + r;
        if (node < NN) {
            unsigned short* orow = h + (size_t)node * 128;
#pragma unroll
            for (int t = 0; t < 8; ++t)
                orow[t * 16 + ln] = f2bf(acc[t][r]);
        }
    }
}

// ---------- agg layer1: 4 dests/wave, group-per-dest, unroll-8 deep gather ----------
__global__ __launch_bounds__(256) void agg1_kernel(const unsigned short* __restrict__ h,
                                                   const float* __restrict__ dinv,
                                                   const int* __restrict__ off,
                                                   const int* __restrict__ epair,
                                                   const void* __restrict__ b1,
                                                   unsigned short* __restrict__ outp,
                                                   const int* __restrict__ flags) {
    int tid = threadIdx.x;
    int lane = tid & 63, wv = tid >> 6;
    int g = lane >> 4, l = lane & 15;   // group = dest, 16 feature-lanes
    int c = blockIdx.x * 16 + wv * 4 + g;
    if (c >= NN) return;
    int bf = flags[0];
    float dc = dinv[c];
    int jb = off[c], je = off[c + 1];
    float acc[8];
    {
        short8 v = *(const short8*)(h + (size_t)c * 128 + l * 8);
        float w = dc * dc;
#pragma unroll
        for (int f = 0; f < 8; ++f) acc[f] = bf2f((unsigned short)v[f]) * w;
    }
    int j = jb;
    for (; j + 7 < je; j += 8) {   // 8 independent row loads in flight
        int si[8];
#pragma unroll
        for (int q = 0; q < 8; ++q) si[q] = epair[j + q];
        short8 v[8];
#pragma unroll
        for (int q = 0; q < 8; ++q)
            v[q] = *(const short8*)(h + (size_t)si[q] * 128 + l * 8);
        float w[8];
#pragma unroll
        for (int q = 0; q < 8; ++q) w[q] = dinv[si[q]] * dc;
#pragma unroll
        for (int q = 0; q < 8; ++q) {
#pragma unroll
            for (int f = 0; f < 8; ++f)
                acc[f] = fmaf(bf2f((unsigned short)v[q][f]), w[q], acc[f]);
        }
    }
    for (; j + 3 < je; j += 4) {
        int s0 = epair[j], s1 = epair[j + 1], s2 = epair[j + 2], s3 = epair[j + 3];
        float w0 = dinv[s0] * dc, w1 = dinv[s1] * dc;
        float w2 = dinv[s2] * dc, w3 = dinv[s3] * dc;
        short8 v0 = *(const short8*)(h + (size_t)s0 * 128 + l * 8);
        short8 v1 = *(const short8*)(h + (size_t)s1 * 128 + l * 8);
        short8 v2 = *(const short8*)(h + (size_t)s2 * 128 + l * 8);
        short8 v3 = *(const short8*)(h + (size_t)s3 * 128 + l * 8);
#pragma unroll
        for (int f = 0; f < 8; ++f) {
            acc[f] = fmaf(bf2f((unsigned short)v0[f]), w0, acc[f]);
            acc[f] = fmaf(bf2f((unsigned short)v1[f]), w1, acc[f]);
            acc[f] = fmaf(bf2f((unsigned short)v2[f]), w2, acc[f]);
            acc[f] = fmaf(bf2f((unsigned short)v3[f]), w3, acc[f]);
        }
    }
    for (; j < je; ++j) {
        int s0 = epair[j];
        float w = dinv[s0] * dc;
        short8 v = *(const short8*)(h + (size_t)s0 * 128 + l * 8);
#pragma unroll
        for (int f = 0; f < 8; ++f) acc[f] = fmaf(bf2f((unsigned short)v[f]), w, acc[f]);
    }
    short8 o;
#pragma unroll
    for (int f = 0; f < 8; ++f)
        o[f] = (short)f2bf(fmaxf(acc[f] + ldf(b1, l * 8 + f, bf), 0.f));
    *(short8*)(outp + (size_t)c * 128 + l * 8) = o;
}

// ---------- GEMM2 (512 thr, 128 rows/block): h2[N,64](bf16) = agg1[N,128] @ W2 ----------
__global__ __launch_bounds__(512) void gemm2_kernel(const unsigned short* __restrict__ a_,
                                                    const unsigned short* __restrict__ wt,
                                                    unsigned short* __restrict__ h2) {
    __shared__ unsigned short wl[64 * 136];  // ~17 KB
    int tid = threadIdx.x;
    for (int i = tid; i < 64 * 16; i += 512) {
        int n = i >> 4, b = i & 15;
        short8 v = *(const short8*)(wt + n * 128 + b * 8);
        *(short8*)(&wl[n * 136 + b * 8]) = v;
    }
    __syncthreads();
    int lane = tid & 63, wv = tid >> 6;       // 0..7
    int ln = lane & 15, kq = lane >> 4;
    int rowBase = blockIdx.x * 128 + wv * 16;
    int anode = min(rowBase + ln, NN - 1);
    const unsigned short* arow = a_ + (size_t)anode * 128;
    f32x4 acc[4];
#pragma unroll
    for (int t = 0; t < 4; ++t) acc[t] = (f32x4)0.f;
#pragma unroll
    for (int ks = 0; ks < 4; ++ks) {
        int k0 = ks * 32 + kq * 8;
        short8 a = *(const short8*)(arow + k0);
#pragma unroll
        for (int t = 0; t < 4; ++t) {
            int n = t * 16 + ln;
            short8 b = *(const short8*)(&wl[n * 136 + k0]);
            acc[t] = __builtin_amdgcn_mfma_f32_16x16x32_bf16(a, b, acc[t], 0, 0, 0);
        }
    }
#pragma unroll
    for (int r = 0; r < 4; ++r) {
        int node = rowBase + kq * 4 + r;
        if (node < NN) {
            unsigned short* orow = h2 + (size_t)node * 64;
#pragma unroll
            for (int t = 0; t < 4; ++t)
                orow[t * 16 + ln] = f2bf(acc[t][r]);
        }
    }
}

// ---------- agg layer2: 8 dests/wave, group-per-dest, unroll-8 deep gather ----------
__global__ __launch_bounds__(256) void agg_out_kernel(const unsigned short* __restrict__ h,
                                                      const float* __restrict__ dinv,
                                                      const int* __restrict__ off,
                                                      const int* __restrict__ epair,
                                                      const void* __restrict__ b2,
                                                      void* __restrict__ outp,
                                                      const int* __restrict__ flags) {
    int tid = threadIdx.x;
    int lane = tid & 63, wv = tid >> 6;
    int g = lane >> 3, l = lane & 7;   // group = dest, 8 feature-lanes
    int c = blockIdx.x * 32 + wv * 8 + g;
    if (c >= NN) return;
    int bf = flags[0];
    float dc = dinv[c];
    int jb = off[c], je = off[c + 1];
    float acc[8];
    {
        short8 v = *(const short8*)(h + (size_t)c * 64 + l * 8);
        float w = dc * dc;
#pragma unroll
        for (int f = 0; f < 8; ++f) acc[f] = bf2f((unsigned short)v[f]) * w;
    }
    int j = jb;
    for (; j + 7 < je; j += 8) {   // 8 independent row loads in flight
        int si[8];
#pragma unroll
        for (int q = 0; q < 8; ++q) si[q] = epair[j + q];
        short8 v[8];
#pragma unroll
        for (int q = 0; q < 8; ++q)
            v[q] = *(const short8*)(h + (size_t)si[q] * 64 + l * 8);
        float w[8];
#pragma unroll
        for (int q = 0; q < 8; ++q) w[q] = dinv[si[q]] * dc;
#pragma unroll
        for (int q = 0; q < 8; ++q) {
#pragma unroll
            for (int f = 0; f < 8; ++f)
                acc[f] = fmaf(bf2f((unsigned short)v[q][f]), w[q], acc[f]);
        }
    }
    for (; j + 3 < je; j += 4) {
        int s0 = epair[j], s1 = epair[j + 1], s2 = epair[j + 2], s3 = epair[j + 3];
        float w0 = dinv[s0] * dc, w1 = dinv[s1] * dc;
        float w2 = dinv[s2] * dc, w3 = dinv[s3] * dc;
        short8 v0 = *(const short8*)(h + (size_t)s0 * 64 + l * 8);
        short8 v1 = *(const short8*)(h + (size_t)s1 * 64 + l * 8);
        short8 v2 = *(const short8*)(h + (size_t)s2 * 64 + l * 8);
        short8 v3 = *(const short8*)(h + (size_t)s3 * 64 + l * 8);
#pragma unroll
        for (int f = 0; f < 8; ++f) {
            acc[f] = fmaf(bf2f((unsigned short)v0[f]), w0, acc[f]);
            acc[f] = fmaf(bf2f((unsigned short)v1[f]), w1, acc[f]);
            acc[f] = fmaf(bf2f((unsigned short)v2[f]), w2, acc[f]);
            acc[f] = fmaf(bf2f((unsigned short)v3[f]), w3, acc[f]);
        }
    }
    for (; j < je; ++j) {
        int s0 = epair[j];
        float w = dinv[s0] * dc;
        short8 v = *(const short8*)(h + (size_t)s0 * 64 + l * 8);
#pragma unroll
        for (int f = 0; f < 8; ++f) acc[f] = fmaf(bf2f((unsigned short)v[f]), w, acc[f]);
    }
    if (bf) {
        short8 o;
#pragma unroll
        for (int f = 0; f < 8; ++f)
            o[f] = (short)f2bf(acc[f] + ldf(b2, l * 8 + f, 1));
        *(short8*)((unsigned short*)outp + (size_t)c * 64 + l * 8) = o;
    } else {
        float* op = (float*)outp + (size_t)c * 64 + l * 8;
#pragma unroll
        for (int f = 0; f < 8; ++f)
            op[f] = acc[f] + ldf(b2, l * 8 + f, 0);
    }
}

extern "C" void kernel_launch(void* const* d_in, const int* in_sizes, int n_in,
                              void* d_out, int out_size, void* d_ws, size_t ws_size,
                              hipStream_t stream) {
    const void* x  = d_in[0];
    const void* ei = d_in[1];
    const void* W1 = d_in[2];
    const void* b1 = d_in[3];
    const void* W2 = d_in[4];
    const void* b2 = d_in[5];

    const int N = NN;
    const int E = in_sizes[1] / 2;
    const int PB = (E + CH - 1) / CH;                  // sort blocks
    const int GB = (N + 127) / 128;                    // gemm blocks (128 rows each)
    const int TB = (128 * 256 + 64 * 128 + 511) / 512; // transpose blocks

    char* ws = (char*)d_ws;
    size_t o = 0;
    auto alloc = [&](size_t bytes) { size_t r = o; o += (bytes + 255) & ~(size_t)255; return r; };
    int*   flags  = (int*)(ws + alloc(256));
    int*   bcnt   = (int*)(ws + alloc((size_t)(NB + 1) * 4));
    int*   bstart = (int*)(ws + alloc((size_t)(NB + 1) * 4));
    int*   off    = (int*)(ws + alloc((size_t)(N + 1) * 4));
    float* dinv   = (float*)(ws + alloc((size_t)N * 4));
    int*   epair  = (int*)(ws + alloc((size_t)E * 4));
    int*   poff   = (int*)(ws + alloc((size_t)PB * (NB + 1) * 4));
    unsigned short* w1t  = (unsigned short*)(ws + alloc(128 * 256 * 2));
    unsigned short* w2t  = (unsigned short*)(ws + alloc(64 * 128 * 2));
    unsigned short* h1   = (unsigned short*)(ws + alloc((size_t)N * 128 * 2));
    unsigned short* agg1 = (unsigned short*)(ws + alloc((size_t)N * 128 * 2));
    unsigned short* h2   = h1;          // reuse (h1 dead after agg1_kernel)
    int* ebin = (int*)agg1;             // staging reuse: E*4 <= N*256 bytes

    detect_kernel<<<1, 256, 0, stream>>>((const unsigned int*)x, (const unsigned int*)ei, flags);
    hipMemsetAsync(bcnt, 0, (size_t)(NB + 1) * 4, stream);
    sort_tr_kernel<<<PB + TB, 512, 0, stream>>>(ei, E, bcnt, poff, ebin, flags, W1, W2, w1t, w2t, PB);
    bscan_kernel<<<1, 512, 0, stream>>>(bcnt, bstart, off, E);
    sg1_kernel<<<GB + NB, 512, 0, stream>>>(ebin, poff, bstart, off, dinv, epair, flags, x, w1t, h1, GB, PB);
    agg1_kernel<<<(N + 15) / 16, 256, 0, stream>>>(h1, dinv, off, epair, b1, agg1, flags);
    gemm2_kernel<<<GB, 512, 0, stream>>>(agg1, w2t, h2);
    agg_out_kernel<<<(N + 31) / 32, 256, 0, stream>>>(h2, dinv, off, epair, b2, d_out, flags);
}

// Round 8
// 335.471 us; speedup vs baseline: 1.1412x; 1.0192x over previous
//
#include <hip/hip_runtime.h>

#define NN 100000
#define BW 256                       // bucket width in nodes (c >> 8)
#define NB ((NN + BW - 1) / BW)      // 391 buckets
#define CH 4096                      // edges per sort block

typedef __attribute__((ext_vector_type(8))) short short8;
typedef __attribute__((ext_vector_type(4))) float f32x4;

// ---------- bf16 helpers ----------
__device__ __forceinline__ float bf2f(unsigned short u) {
    union { unsigned int i; float f; } v;
    v.i = ((unsigned int)u) << 16;
    return v.f;
}
__device__ __forceinline__ unsigned short f2bf(float f) {
    unsigned int u = __float_as_uint(f);
    unsigned int r = u + 0x7fffu + ((u >> 16) & 1u);  // RNE
    return (unsigned short)(r >> 16);
}
// flags[0]=1 -> float tensors are bf16, else fp32
__device__ __forceinline__ float ldf(const void* p, int i, int bf) {
    return bf ? bf2f(((const unsigned short*)p)[i]) : ((const float*)p)[i];
}
// flags[1]=1 -> edge_index is int64, else int32
__device__ __forceinline__ int lde(const void* p, int i, int i64f) {
    return i64f ? (int)((const long long*)p)[i] : ((const int*)p)[i];
}
// load 8 consecutive float-typed input elements as bf16 short8 (flag-driven)
__device__ __forceinline__ short8 ld8bf(const void* p, size_t i, int bf) {
    if (bf) return *(const short8*)((const unsigned short*)p + i);
    const float* f = (const float*)p + i;
    f32x4 a = *(const f32x4*)f;
    f32x4 b = *(const f32x4*)(f + 4);
    short8 o;
    o[0] = (short)f2bf(a[0]); o[1] = (short)f2bf(a[1]);
    o[2] = (short)f2bf(a[2]); o[3] = (short)f2bf(a[3]);
    o[4] = (short)f2bf(b[0]); o[5] = (short)f2bf(b[1]);
    o[6] = (short)f2bf(b[2]); o[7] = (short)f2bf(b[3]);
    return o;
}

// ---------- dtype detection (parallel, 1 block) ----------
__global__ void detect_kernel(const unsigned int* __restrict__ xw,
                              const unsigned int* __restrict__ eiw,
                              int* __restrict__ flags) {
    __shared__ int s0, s1;
    int tid = threadIdx.x;
    if (tid == 0) { s0 = 0; s1 = 0; }
    __syncthreads();
    if (tid < 128) {
        unsigned int w = xw[tid];
        int e = (int)((w >> 7) & 0xFFu);
        if (e < 100 || e > 130) atomicAdd(&s0, 1);
    } else if (tid < 192) {
        if (eiw[2 * (tid - 128) + 1] == 0u) atomicAdd(&s1, 1);
    }
    __syncthreads();
    if (tid == 0) {
        flags[0] = (s0 < 16) ? 1 : 0;
        flags[1] = (s1 >= 48) ? 1 : 0;
    }
}

// ---------- fused: block-local bucket sort of edges + weight transpose ----------
__global__ __launch_bounds__(512) void sort_tr_kernel(const void* __restrict__ ei, int E,
                                                      int* __restrict__ bcnt,
                                                      int* __restrict__ poff,
                                                      int* __restrict__ ebin,
                                                      const int* __restrict__ flags,
                                                      const void* __restrict__ w1,
                                                      const void* __restrict__ w2,
                                                      unsigned short* __restrict__ w1t,
                                                      unsigned short* __restrict__ w2t,
                                                      int PB) {
    __shared__ int lc[NB + 1];
    __shared__ int ls[512];
    __shared__ int sbuf[CH];
    int bid = blockIdx.x, tid = threadIdx.x;
    if (bid < PB) {
        int i64f = flags[1];
        int base = bid * CH;
        int cntE = min(CH, E - base);
        int re[CH / 512], ce[CH / 512];
        for (int i = tid; i < NB; i += 512) lc[i] = 0;
        __syncthreads();
#pragma unroll
        for (int q = 0; q < CH / 512; ++q) {
            int e = base + q * 512 + tid;
            if (e < E) {
                int r = lde(ei, e, i64f);
                int c = lde(ei, E + e, i64f);
                r = min(max(r, 0), NN - 1);
                c = min(max(c, 0), NN - 1);
                re[q] = r; ce[q] = c;
                atomicAdd(&lc[c >> 8], 1);
            } else {
                re[q] = -1; ce[q] = 0;
            }
        }
        __syncthreads();
        int v = (tid < NB) ? lc[tid] : 0;
        ls[tid] = v;
        __syncthreads();
        for (int o = 1; o < 512; o <<= 1) {
            int t = (tid >= o) ? ls[tid - o] : 0;
            __syncthreads();
            ls[tid] += t;
            __syncthreads();
        }
        int excl = ls[tid] - v;
        if (tid < NB) {
            poff[bid * (NB + 1) + tid] = excl;
            if (v) atomicAdd(&bcnt[tid], v);
        }
        if (tid == 0) poff[bid * (NB + 1) + NB] = cntE;
        __syncthreads();
        if (tid < NB) lc[tid] = excl;  // cursor
        __syncthreads();
#pragma unroll
        for (int q = 0; q < CH / 512; ++q) {
            if (re[q] >= 0) {
                int pos = atomicAdd(&lc[ce[q] >> 8], 1);
                sbuf[pos] = (re[q] << 8) | (ce[q] & 255);
            }
        }
        __syncthreads();
        for (int i = tid; i < cntE; i += 512)
            ebin[base + i] = sbuf[i];
    } else {
        int bf = flags[0];
        int i = (bid - PB) * 512 + tid;
        if (i < 128 * 256) {
            int n = i >> 8, k = i & 255;
            w1t[n * 256 + k] = f2bf(ldf(w1, k * 128 + n, bf));
        } else if (i < 128 * 256 + 64 * 128) {
            int j = i - 128 * 256;
            int n = j >> 7, k = j & 127;
            w2t[n * 128 + k] = f2bf(ldf(w2, k * 64 + n, bf));
        }
    }
}

// ---------- bucket prefix scan (1 block of 512) ----------
__global__ void bscan_kernel(const int* __restrict__ bcnt, int* __restrict__ bstart,
                             int* __restrict__ off, int E) {
    __shared__ int s[512];
    int tid = threadIdx.x;
    int v = (tid < NB) ? bcnt[tid] : 0;
    s[tid] = v;
    __syncthreads();
    for (int o = 1; o < 512; o <<= 1) {
        int t = (tid >= o) ? s[tid - o] : 0;
        __syncthreads();
        s[tid] += t;
        __syncthreads();
    }
    int excl = s[tid] - v;
    if (tid < NB) bstart[tid] = excl;
    if (tid == NB - 1) bstart[NB] = excl + v;  // == E
    if (tid == 0) off[NN] = E;
}

// ---------- fused: per-bucket CSR build (L2-local) + GEMM1 (512 thr, 128 rows/block) ----------
__global__ __launch_bounds__(512) void sg1_kernel(const int* __restrict__ ebin,
                                                  const int* __restrict__ poff,
                                                  const int* __restrict__ bstart,
                                                  int* __restrict__ off,
                                                  float* __restrict__ dinv,
                                                  int* __restrict__ epair,
                                                  const int* __restrict__ flags,
                                                  const void* __restrict__ x,
                                                  const unsigned short* __restrict__ wt,
                                                  unsigned short* __restrict__ h,
                                                  int GB, int PB) {
    __shared__ unsigned short wl[128 * 136];  // 34.8 KB (gemm path)
    __shared__ int cnt[BW], pfx[BW];          // csr path
    int bid = blockIdx.x, tid = threadIdx.x;
    bool isC = ((bid % 3) == 0) && (bid / 3 < NB);
    if (isC) {
        // -------- CSR path: bucket b, gather segments from each sort block --------
        int b = bid / 3;
        int c0 = b << 8;
        int s = bstart[b];
        for (int i = tid; i < BW; i += 512) cnt[i] = 0;
        __syncthreads();
        for (int p = tid; p < PB; p += 512) {
            const int* pr = poff + p * (NB + 1);
            int s0 = p * CH + pr[b], s1 = p * CH + pr[b + 1];
            for (int i = s0; i < s1; ++i)
                atomicAdd(&cnt[ebin[i] & 255], 1);
        }
        __syncthreads();
        int v = (tid < BW) ? cnt[tid] : 0;
        if (tid < BW) pfx[tid] = v;
        __syncthreads();
        for (int o = 1; o < BW; o <<= 1) {
            int t = (tid < BW && tid >= o) ? pfx[tid - o] : 0;
            __syncthreads();
            if (tid < BW) pfx[tid] += t;
            __syncthreads();
        }
        if (tid < BW) {
            int basec = s + pfx[tid] - v;   // exclusive prefix -> global CSR offset
            int node = c0 + tid;
            if (node < NN) {
                off[node] = basec;
                dinv[node] = rsqrtf((float)(v + 1));  // +1 self loop
            }
            cnt[tid] = basec;  // becomes cursor
        }
        __syncthreads();
        for (int p = tid; p < PB; p += 512) {
            const int* pr = poff + p * (NB + 1);
            int s0 = p * CH + pr[b], s1 = p * CH + pr[b + 1];
            for (int i = s0; i < s1; ++i) {
                int w = ebin[i];
                int pos = atomicAdd(&cnt[w & 255], 1);
                epair[pos] = w >> 8;
            }
        }
        return;
    }
    // -------- gemm1 path: 8 waves x 16 rows = 128 rows/block, W1 staged in LDS --------
    int gb = bid - min(bid / 3 + 1, NB);
    int bf = flags[0];
    int lane = tid & 63, wv = tid >> 6;       // wv in 0..7
    int ln = lane & 15, kq = lane >> 4;
    int rowBase = gb * 128 + wv * 16;
    int anode = min(rowBase + ln, NN - 1);
    size_t abase = (size_t)anode * 256;
    f32x4 acc[8];
#pragma unroll
    for (int t = 0; t < 8; ++t) acc[t] = (f32x4)0.f;

    for (int half = 0; half < 2; ++half) {
        __syncthreads();
        for (int i = tid; i < 128 * 16; i += 512) {
            int n = i >> 4, b = i & 15;
            short8 v = *(const short8*)(wt + n * 256 + half * 128 + b * 8);
            *(short8*)(&wl[n * 136 + b * 8]) = v;
        }
        __syncthreads();
#pragma unroll
        for (int ks = 0; ks < 4; ++ks) {
            int klocal = ks * 32 + kq * 8;
            short8 a = ld8bf(x, abase + half * 128 + klocal, bf);
#pragma unroll
            for (int t = 0; t < 8; ++t) {
                int n = t * 16 + ln;
                short8 b = *(const short8*)(&wl[n * 136 + klocal]);
                acc[t] = __builtin_amdgcn_mfma_f32_16x16x32_bf16(a, b, acc[t], 0, 0, 0);
            }
        }
    }
#pragma unroll
    for (int r = 0; r < 4; ++r) {
        int node = rowBase + kq * 4 + r;
        if (node < NN) {
            unsigned short* orow = h + (size_t)node * 128;
#pragma unroll
            for (int t = 0; t < 8; ++t)
                orow[t * 16 + ln] = f2bf(acc[t][r]);
        }
    }
}

// ---------- fused agg1 + GEMM2: per 16-dest block, gather+relu into LDS, then MFMA @ W2 ----------
__global__ __launch_bounds__(256) void ag1_kernel(const unsigned short* __restrict__ h,
                                                  const float* __restrict__ dinv,
                                                  const int* __restrict__ off,
                                                  const int* __restrict__ epair,
                                                  const void* __restrict__ b1,
                                                  const unsigned short* __restrict__ w2t,
                                                  unsigned short* __restrict__ h2,
                                                  const int* __restrict__ flags) {
    __shared__ unsigned short sA[16 * 136];  // 16 relu'd agg rows (bf16), padded
    int tid = threadIdx.x;
    int lane = tid & 63, wv = tid >> 6;
    int g = lane >> 4, l = lane & 15;   // group = dest, 16 feature-lanes
    int cb0 = blockIdx.x * 16;
    int c = cb0 + wv * 4 + g;
    int bf = flags[0];
    float acc[8];
#pragma unroll
    for (int f = 0; f < 8; ++f) acc[f] = 0.f;
    if (c < NN) {
        float dc = dinv[c];
        int jb = off[c], je = off[c + 1];
        {
            short8 v = *(const short8*)(h + (size_t)c * 128 + l * 8);
            float w = dc * dc;
#pragma unroll
            for (int f = 0; f < 8; ++f) acc[f] = bf2f((unsigned short)v[f]) * w;
        }
        int j = jb;
        for (; j + 3 < je; j += 4) {
            int s0 = epair[j], s1 = epair[j + 1], s2 = epair[j + 2], s3 = epair[j + 3];
            float w0 = dinv[s0] * dc, w1 = dinv[s1] * dc;
            float w2 = dinv[s2] * dc, w3 = dinv[s3] * dc;
            short8 v0 = *(const short8*)(h + (size_t)s0 * 128 + l * 8);
            short8 v1 = *(const short8*)(h + (size_t)s1 * 128 + l * 8);
            short8 v2 = *(const short8*)(h + (size_t)s2 * 128 + l * 8);
            short8 v3 = *(const short8*)(h + (size_t)s3 * 128 + l * 8);
#pragma unroll
            for (int f = 0; f < 8; ++f) {
                acc[f] = fmaf(bf2f((unsigned short)v0[f]), w0, acc[f]);
                acc[f] = fmaf(bf2f((unsigned short)v1[f]), w1, acc[f]);
                acc[f] = fmaf(bf2f((unsigned short)v2[f]), w2, acc[f]);
                acc[f] = fmaf(bf2f((unsigned short)v3[f]), w3, acc[f]);
            }
        }
        for (; j < je; ++j) {
            int s0 = epair[j];
            float w = dinv[s0] * dc;
            short8 v = *(const short8*)(h + (size_t)s0 * 128 + l * 8);
#pragma unroll
            for (int f = 0; f < 8; ++f) acc[f] = fmaf(bf2f((unsigned short)v[f]), w, acc[f]);
        }
    }
    // relu + bias -> LDS tile row
    {
        short8 o;
#pragma unroll
        for (int f = 0; f < 8; ++f)
            o[f] = (short)f2bf(fmaxf(acc[f] + ldf(b1, l * 8 + f, bf), 0.f));
        *(short8*)(&sA[(wv * 4 + g) * 136 + l * 8]) = o;
    }
    __syncthreads();
    // ---- GEMM2 on the 16-row tile: wave wv owns output n-tile wv (16 cols) ----
    int ln = lane & 15, kq = lane >> 4;
    f32x4 a2 = (f32x4)0.f;
#pragma unroll
    for (int ks = 0; ks < 4; ++ks) {
        int k0 = ks * 32 + kq * 8;
        short8 a = *(const short8*)(&sA[ln * 136 + k0]);
        short8 b = *(const short8*)(w2t + (wv * 16 + ln) * 128 + k0);
        a2 = __builtin_amdgcn_mfma_f32_16x16x32_bf16(a, b, a2, 0, 0, 0);
    }
#pragma unroll
    for (int r = 0; r < 4; ++r) {
        int node = cb0 + kq * 4 + r;
        if (node < NN)
            h2[(size_t)node * 64 + wv * 16 + ln] = f2bf(a2[r]);
    }
}

// ---------- agg layer2: 8 dests/wave, group-per-dest, unroll-4 batched gather ----------
__global__ __launch_bounds__(256) void agg_out_kernel(const unsigned short* __restrict__ h,
                                                      const float* __restrict__ dinv,
                                                      const int* __restrict__ off,
                                                      const int* __restrict__ epair,
                                                      const void* __restrict__ b2,
                                                      void* __restrict__ outp,
                                                      const int* __restrict__ flags) {
    int tid = threadIdx.x;
    int lane = tid & 63, wv = tid >> 6;
    int g = lane >> 3, l = lane & 7;   // group = dest, 8 feature-lanes
    int c = blockIdx.x * 32 + wv * 8 + g;
    if (c >= NN) return;
    int bf = flags[0];
    float dc = dinv[c];
    int jb = off[c], je = off[c + 1];
    float acc[8];
    {
        short8 v = *(const short8*)(h + (size_t)c * 64 + l * 8);
        float w = dc * dc;
#pragma unroll
        for (int f = 0; f < 8; ++f) acc[f] = bf2f((unsigned short)v[f]) * w;
    }
    int j = jb;
    for (; j + 3 < je; j += 4) {
        int s0 = epair[j], s1 = epair[j + 1], s2 = epair[j + 2], s3 = epair[j + 3];
        float w0 = dinv[s0] * dc, w1 = dinv[s1] * dc;
        float w2 = dinv[s2] * dc, w3 = dinv[s3] * dc;
        short8 v0 = *(const short8*)(h + (size_t)s0 * 64 + l * 8);
        short8 v1 = *(const short8*)(h + (size_t)s1 * 64 + l * 8);
        short8 v2 = *(const short8*)(h + (size_t)s2 * 64 + l * 8);
        short8 v3 = *(const short8*)(h + (size_t)s3 * 64 + l * 8);
#pragma unroll
        for (int f = 0; f < 8; ++f) {
            acc[f] = fmaf(bf2f((unsigned short)v0[f]), w0, acc[f]);
            acc[f] = fmaf(bf2f((unsigned short)v1[f]), w1, acc[f]);
            acc[f] = fmaf(bf2f((unsigned short)v2[f]), w2, acc[f]);
            acc[f] = fmaf(bf2f((unsigned short)v3[f]), w3, acc[f]);
        }
    }
    for (; j < je; ++j) {
        int s0 = epair[j];
        float w = dinv[s0] * dc;
        short8 v = *(const short8*)(h + (size_t)s0 * 64 + l * 8);
#pragma unroll
        for (int f = 0; f < 8; ++f) acc[f] = fmaf(bf2f((unsigned short)v[f]), w, acc[f]);
    }
    if (bf) {
        short8 o;
#pragma unroll
        for (int f = 0; f < 8; ++f)
            o[f] = (short)f2bf(acc[f] + ldf(b2, l * 8 + f, 1));
        *(short8*)((unsigned short*)outp + (size_t)c * 64 + l * 8) = o;
    } else {
        float* op = (float*)outp + (size_t)c * 64 + l * 8;
#pragma unroll
        for (int f = 0; f < 8; ++f)
            op[f] = acc[f] + ldf(b2, l * 8 + f, 0);
    }
}

extern "C" void kernel_launch(void* const* d_in, const int* in_sizes, int n_in,
                              void* d_out, int out_size, void* d_ws, size_t ws_size,
                              hipStream_t stream) {
    const void* x  = d_in[0];
    const void* ei = d_in[1];
    const void* W1 = d_in[2];
    const void* b1 = d_in[3];
    const void* W2 = d_in[4];
    const void* b2 = d_in[5];

    const int N = NN;
    const int E = in_sizes[1] / 2;
    const int PB = (E + CH - 1) / CH;                  // sort blocks
    const int GB = (N + 127) / 128;                    // gemm blocks (128 rows each)
    const int TB = (128 * 256 + 64 * 128 + 511) / 512; // transpose blocks

    char* ws = (char*)d_ws;
    size_t o = 0;
    auto alloc = [&](size_t bytes) { size_t r = o; o += (bytes + 255) & ~(size_t)255; return r; };
    int*   flags  = (int*)(ws + alloc(256));
    int*   bcnt   = (int*)(ws + alloc((size_t)(NB + 1) * 4));
    int*   bstart = (int*)(ws + alloc((size_t)(NB + 1) * 4));
    int*   off    = (int*)(ws + alloc((size_t)(N + 1) * 4));
    float* dinv   = (float*)(ws + alloc((size_t)N * 4));
    int*   epair  = (int*)(ws + alloc((size_t)E * 4));
    int*   poff   = (int*)(ws + alloc((size_t)PB * (NB + 1) * 4));
    unsigned short* w1t  = (unsigned short*)(ws + alloc(128 * 256 * 2));
    unsigned short* w2t  = (unsigned short*)(ws + alloc(64 * 128 * 2));
    unsigned short* h1   = (unsigned short*)(ws + alloc((size_t)N * 128 * 2));
    unsigned short* buf2 = (unsigned short*)(ws + alloc((size_t)N * 128 * 2));
    unsigned short* h2   = buf2;        // h2 lives in buf2 (h1 stays live during ag1)
    int* ebin = (int*)buf2;             // staging reuse: ebin dead before ag1 writes h2

    detect_kernel<<<1, 256, 0, stream>>>((const unsigned int*)x, (const unsigned int*)ei, flags);
    hipMemsetAsync(bcnt, 0, (size_t)(NB + 1) * 4, stream);
    sort_tr_kernel<<<PB + TB, 512, 0, stream>>>(ei, E, bcnt, poff, ebin, flags, W1, W2, w1t, w2t, PB);
    bscan_kernel<<<1, 512, 0, stream>>>(bcnt, bstart, off, E);
    sg1_kernel<<<GB + NB, 512, 0, stream>>>(ebin, poff, bstart, off, dinv, epair, flags, x, w1t, h1, GB, PB);
    ag1_kernel<<<(N + 15) / 16, 256, 0, stream>>>(h1, dinv, off, epair, b1, w2t, h2, flags);
    agg_out_kernel<<<(N + 31) / 32, 256, 0, stream>>>(h2, dinv, off, epair, b2, d_out, flags);
}

// Round 9
// 328.448 us; speedup vs baseline: 1.1656x; 1.0214x over previous
//
#include <hip/hip_runtime.h>

#define NN 100000
#define BW 256                       // bucket width in nodes (c >> 8)
#define NB ((NN + BW - 1) / BW)      // 391 buckets
#define CH 4096                      // edges per sort block

typedef __attribute__((ext_vector_type(8))) short short8;
typedef __attribute__((ext_vector_type(4))) float f32x4;

// ---------- bf16 helpers ----------
__device__ __forceinline__ float bf2f(unsigned short u) {
    union { unsigned int i; float f; } v;
    v.i = ((unsigned int)u) << 16;
    return v.f;
}
__device__ __forceinline__ unsigned short f2bf(float f) {
    unsigned int u = __float_as_uint(f);
    unsigned int r = u + 0x7fffu + ((u >> 16) & 1u);  // RNE
    return (unsigned short)(r >> 16);
}
// flags[0]=1 -> float tensors are bf16, else fp32
__device__ __forceinline__ float ldf(const void* p, int i, int bf) {
    return bf ? bf2f(((const unsigned short*)p)[i]) : ((const float*)p)[i];
}
// flags[1]=1 -> edge_index is int64, else int32
__device__ __forceinline__ int lde(const void* p, int i, int i64f) {
    return i64f ? (int)((const long long*)p)[i] : ((const int*)p)[i];
}
// load 8 consecutive float-typed input elements as bf16 short8 (flag-driven)
__device__ __forceinline__ short8 ld8bf(const void* p, size_t i, int bf) {
    if (bf) return *(const short8*)((const unsigned short*)p + i);
    const float* f = (const float*)p + i;
    f32x4 a = *(const f32x4*)f;
    f32x4 b = *(const f32x4*)(f + 4);
    short8 o;
    o[0] = (short)f2bf(a[0]); o[1] = (short)f2bf(a[1]);
    o[2] = (short)f2bf(a[2]); o[3] = (short)f2bf(a[3]);
    o[4] = (short)f2bf(b[0]); o[5] = (short)f2bf(b[1]);
    o[6] = (short)f2bf(b[2]); o[7] = (short)f2bf(b[3]);
    return o;
}

// ---------- fused: dtype detect (per block) + bucket sort of edges + weight transpose ----------
__global__ __launch_bounds__(512) void sort_tr_kernel(const void* __restrict__ ei, int E,
                                                      int* __restrict__ bcnt,
                                                      int* __restrict__ poff,
                                                      int* __restrict__ ebin,
                                                      int* __restrict__ flags,
                                                      const void* __restrict__ x,
                                                      const void* __restrict__ w1,
                                                      const void* __restrict__ w2,
                                                      unsigned short* __restrict__ w1t,
                                                      unsigned short* __restrict__ w2t,
                                                      int PB) {
    __shared__ int lc[NB + 1];
    __shared__ int ls[512];
    __shared__ int sbuf[CH];
    __shared__ int sf[2];
    int bid = blockIdx.x, tid = threadIdx.x;
    // ---- local dtype detection (replaces detect_kernel) ----
    if (tid == 0) { sf[0] = 0; sf[1] = 0; }
    __syncthreads();
    if (tid < 128) {
        unsigned int w = ((const unsigned int*)x)[tid];
        int e = (int)((w >> 7) & 0xFFu);
        if (e < 100 || e > 130) atomicAdd(&sf[0], 1);
    } else if (tid < 192) {
        if (((const unsigned int*)ei)[2 * (tid - 128) + 1] == 0u) atomicAdd(&sf[1], 1);
    }
    __syncthreads();
    int bf = (sf[0] < 16) ? 1 : 0;
    int i64f = (sf[1] >= 48) ? 1 : 0;
    if (bid == 0 && tid == 0) { flags[0] = bf; flags[1] = i64f; }

    if (bid < PB) {
        int base = bid * CH;
        int cntE = min(CH, E - base);
        int re[CH / 512], ce[CH / 512];
        for (int i = tid; i < NB; i += 512) lc[i] = 0;
        __syncthreads();
#pragma unroll
        for (int q = 0; q < CH / 512; ++q) {
            int e = base + q * 512 + tid;
            if (e < E) {
                int r = lde(ei, e, i64f);
                int c = lde(ei, E + e, i64f);
                r = min(max(r, 0), NN - 1);
                c = min(max(c, 0), NN - 1);
                re[q] = r; ce[q] = c;
                atomicAdd(&lc[c >> 8], 1);
            } else {
                re[q] = -1; ce[q] = 0;
            }
        }
        __syncthreads();
        int v = (tid < NB) ? lc[tid] : 0;
        ls[tid] = v;
        __syncthreads();
        for (int o = 1; o < 512; o <<= 1) {
            int t = (tid >= o) ? ls[tid - o] : 0;
            __syncthreads();
            ls[tid] += t;
            __syncthreads();
        }
        int excl = ls[tid] - v;
        if (tid < NB) {
            poff[bid * (NB + 1) + tid] = excl;
            if (v) atomicAdd(&bcnt[tid], v);
        }
        if (tid == 0) poff[bid * (NB + 1) + NB] = cntE;
        __syncthreads();
        if (tid < NB) lc[tid] = excl;  // cursor
        __syncthreads();
#pragma unroll
        for (int q = 0; q < CH / 512; ++q) {
            if (re[q] >= 0) {
                int pos = atomicAdd(&lc[ce[q] >> 8], 1);
                sbuf[pos] = (re[q] << 8) | (ce[q] & 255);
            }
        }
        __syncthreads();
        for (int i = tid; i < cntE; i += 512)
            ebin[base + i] = sbuf[i];
    } else {
        int i = (bid - PB) * 512 + tid;
        if (i < 128 * 256) {
            int n = i >> 8, k = i & 255;
            w1t[n * 256 + k] = f2bf(ldf(w1, k * 128 + n, bf));
        } else if (i < 128 * 256 + 64 * 128) {
            int j = i - 128 * 256;
            int n = j >> 7, k = j & 127;
            w2t[n * 128 + k] = f2bf(ldf(w2, k * 64 + n, bf));
        }
    }
}

// ---------- fused: per-bucket CSR build (self-computed bucket prefix) + GEMM1 ----------
__global__ __launch_bounds__(512) void sg1_kernel(const int* __restrict__ ebin,
                                                  const int* __restrict__ poff,
                                                  const int* __restrict__ bcnt,
                                                  int* __restrict__ off,
                                                  float* __restrict__ dinv,
                                                  int* __restrict__ epair,
                                                  const int* __restrict__ flags,
                                                  const void* __restrict__ x,
                                                  const unsigned short* __restrict__ wt,
                                                  unsigned short* __restrict__ h,
                                                  int GB, int PB) {
    __shared__ unsigned short wl[128 * 136];  // 34.8 KB (gemm path)
    __shared__ int cnt[BW], pfx[BW];          // csr path
    __shared__ int ls2[512];                  // csr path: bucket prefix
    int bid = blockIdx.x, tid = threadIdx.x;
    bool isC = ((bid % 3) == 0) && (bid / 3 < NB);
    if (isC) {
        // -------- CSR path: bucket b --------
        int b = bid / 3;
        int c0 = b << 8;
        // bucket-prefix scan over bcnt (replaces bscan_kernel)
        int bv = (tid < NB) ? bcnt[tid] : 0;
        ls2[tid] = bv;
        __syncthreads();
        for (int o = 1; o < 512; o <<= 1) {
            int t = (tid >= o) ? ls2[tid - o] : 0;
            __syncthreads();
            ls2[tid] += t;
            __syncthreads();
        }
        int s = (b > 0) ? ls2[b - 1] : 0;   // exclusive prefix = bucket start
        if (b == NB - 1 && tid == 0) off[NN] = ls2[NB - 1];
        for (int i = tid; i < BW; i += 512) cnt[i] = 0;
        __syncthreads();
        for (int p = tid; p < PB; p += 512) {
            const int* pr = poff + p * (NB + 1);
            int s0 = p * CH + pr[b], s1 = p * CH + pr[b + 1];
            for (int i = s0; i < s1; ++i)
                atomicAdd(&cnt[ebin[i] & 255], 1);
        }
        __syncthreads();
        int v = (tid < BW) ? cnt[tid] : 0;
        if (tid < BW) pfx[tid] = v;
        __syncthreads();
        for (int o = 1; o < BW; o <<= 1) {
            int t = (tid < BW && tid >= o) ? pfx[tid - o] : 0;
            __syncthreads();
            if (tid < BW) pfx[tid] += t;
            __syncthreads();
        }
        if (tid < BW) {
            int basec = s + pfx[tid] - v;   // exclusive prefix -> global CSR offset
            int node = c0 + tid;
            if (node < NN) {
                off[node] = basec;
                dinv[node] = rsqrtf((float)(v + 1));  // +1 self loop
            }
            cnt[tid] = basec;  // becomes cursor
        }
        __syncthreads();
        for (int p = tid; p < PB; p += 512) {
            const int* pr = poff + p * (NB + 1);
            int s0 = p * CH + pr[b], s1 = p * CH + pr[b + 1];
            for (int i = s0; i < s1; ++i) {
                int w = ebin[i];
                int pos = atomicAdd(&cnt[w & 255], 1);
                epair[pos] = w >> 8;
            }
        }
        return;
    }
    // -------- gemm1 path: 8 waves x 16 rows = 128 rows/block, a-fragments prefetched --------
    int gb = bid - min(bid / 3 + 1, NB);
    int bf = flags[0];
    int lane = tid & 63, wv = tid >> 6;       // wv in 0..7
    int ln = lane & 15, kq = lane >> 4;
    int rowBase = gb * 128 + wv * 16;
    int anode = min(rowBase + ln, NN - 1);
    size_t abase = (size_t)anode * 256;
    // prefetch half-0 A fragments (hides HBM latency under staging)
    short8 a0[4];
#pragma unroll
    for (int q = 0; q < 4; ++q)
        a0[q] = ld8bf(x, abase + q * 32 + kq * 8, bf);
    f32x4 acc[8];
#pragma unroll
    for (int t = 0; t < 8; ++t) acc[t] = (f32x4)0.f;

    // ---- half 0 ----
    __syncthreads();
    for (int i = tid; i < 128 * 16; i += 512) {
        int n = i >> 4, b = i & 15;
        short8 v = *(const short8*)(wt + n * 256 + b * 8);
        *(short8*)(&wl[n * 136 + b * 8]) = v;
    }
    __syncthreads();
    // prefetch half-1 A fragments (overlaps with half-0 MFMA)
    short8 a1[4];
#pragma unroll
    for (int q = 0; q < 4; ++q)
        a1[q] = ld8bf(x, abase + 128 + q * 32 + kq * 8, bf);
#pragma unroll
    for (int ks = 0; ks < 4; ++ks) {
        int klocal = ks * 32 + kq * 8;
#pragma unroll
        for (int t = 0; t < 8; ++t) {
            int n = t * 16 + ln;
            short8 b = *(const short8*)(&wl[n * 136 + klocal]);
            acc[t] = __builtin_amdgcn_mfma_f32_16x16x32_bf16(a0[ks], b, acc[t], 0, 0, 0);
        }
    }
    // ---- half 1 ----
    __syncthreads();
    for (int i = tid; i < 128 * 16; i += 512) {
        int n = i >> 4, b = i & 15;
        short8 v = *(const short8*)(wt + n * 256 + 128 + b * 8);
        *(short8*)(&wl[n * 136 + b * 8]) = v;
    }
    __syncthreads();
#pragma unroll
    for (int ks = 0; ks < 4; ++ks) {
        int klocal = ks * 32 + kq * 8;
#pragma unroll
        for (int t = 0; t < 8; ++t) {
            int n = t * 16 + ln;
            short8 b = *(const short8*)(&wl[n * 136 + klocal]);
            acc[t] = __builtin_amdgcn_mfma_f32_16x16x32_bf16(a1[ks], b, acc[t], 0, 0, 0);
        }
    }
#pragma unroll
    for (int r = 0; r < 4; ++r) {
        int node = rowBase + kq * 4 + r;
        if (node < NN) {
            unsigned short* orow = h + (size_t)node * 128;
#pragma unroll
            for (int t = 0; t < 8; ++t)
                orow[t * 16 + ln] = f2bf(acc[t][r]);
        }
    }
}

// ---------- fused agg1 + GEMM2: per 16-dest block, gather+relu into LDS, then MFMA @ W2 ----------
__global__ __launch_bounds__(256) void ag1_kernel(const unsigned short* __restrict__ h,
                                                  const float* __restrict__ dinv,
                                                  const int* __restrict__ off,
                                                  const int* __restrict__ epair,
                                                  const void* __restrict__ b1,
                                                  const unsigned short* __restrict__ w2t,
                                                  unsigned short* __restrict__ h2,
                                                  const int* __restrict__ flags) {
    __shared__ unsigned short sA[16 * 136];  // 16 relu'd agg rows (bf16), padded
    int tid = threadIdx.x;
    int lane = tid & 63, wv = tid >> 6;
    int g = lane >> 4, l = lane & 15;   // group = dest, 16 feature-lanes
    int cb0 = blockIdx.x * 16;
    int c = cb0 + wv * 4 + g;
    int bf = flags[0];
    float acc[8];
#pragma unroll
    for (int f = 0; f < 8; ++f) acc[f] = 0.f;
    if (c < NN) {
        float dc = dinv[c];
        int jb = off[c], je = off[c + 1];
        {
            short8 v = *(const short8*)(h + (size_t)c * 128 + l * 8);
            float w = dc * dc;
#pragma unroll
            for (int f = 0; f < 8; ++f) acc[f] = bf2f((unsigned short)v[f]) * w;
        }
        int j = jb;
        for (; j + 3 < je; j += 4) {
            int s0 = epair[j], s1 = epair[j + 1], s2 = epair[j + 2], s3 = epair[j + 3];
            float w0 = dinv[s0] * dc, w1 = dinv[s1] * dc;
            float w2 = dinv[s2] * dc, w3 = dinv[s3] * dc;
            short8 v0 = *(const short8*)(h + (size_t)s0 * 128 + l * 8);
            short8 v1 = *(const short8*)(h + (size_t)s1 * 128 + l * 8);
            short8 v2 = *(const short8*)(h + (size_t)s2 * 128 + l * 8);
            short8 v3 = *(const short8*)(h + (size_t)s3 * 128 + l * 8);
#pragma unroll
            for (int f = 0; f < 8; ++f) {
                acc[f] = fmaf(bf2f((unsigned short)v0[f]), w0, acc[f]);
                acc[f] = fmaf(bf2f((unsigned short)v1[f]), w1, acc[f]);
                acc[f] = fmaf(bf2f((unsigned short)v2[f]), w2, acc[f]);
                acc[f] = fmaf(bf2f((unsigned short)v3[f]), w3, acc[f]);
            }
        }
        for (; j < je; ++j) {
            int s0 = epair[j];
            float w = dinv[s0] * dc;
            short8 v = *(const short8*)(h + (size_t)s0 * 128 + l * 8);
#pragma unroll
            for (int f = 0; f < 8; ++f) acc[f] = fmaf(bf2f((unsigned short)v[f]), w, acc[f]);
        }
    }
    // relu + bias -> LDS tile row
    {
        short8 o;
#pragma unroll
        for (int f = 0; f < 8; ++f)
            o[f] = (short)f2bf(fmaxf(acc[f] + ldf(b1, l * 8 + f, bf), 0.f));
        *(short8*)(&sA[(wv * 4 + g) * 136 + l * 8]) = o;
    }
    __syncthreads();
    // ---- GEMM2 on the 16-row tile: wave wv owns output n-tile wv (16 cols) ----
    int ln = lane & 15, kq = lane >> 4;
    f32x4 a2 = (f32x4)0.f;
#pragma unroll
    for (int ks = 0; ks < 4; ++ks) {
        int k0 = ks * 32 + kq * 8;
        short8 a = *(const short8*)(&sA[ln * 136 + k0]);
        short8 b = *(const short8*)(w2t + (wv * 16 + ln) * 128 + k0);
        a2 = __builtin_amdgcn_mfma_f32_16x16x32_bf16(a, b, a2, 0, 0, 0);
    }
#pragma unroll
    for (int r = 0; r < 4; ++r) {
        int node = cb0 + kq * 4 + r;
        if (node < NN)
            h2[(size_t)node * 64 + wv * 16 + ln] = f2bf(a2[r]);
    }
}

// ---------- agg layer2: 8 dests/wave, group-per-dest, unroll-4 batched gather ----------
__global__ __launch_bounds__(256) void agg_out_kernel(const unsigned short* __restrict__ h,
                                                      const float* __restrict__ dinv,
                                                      const int* __restrict__ off,
                                                      const int* __restrict__ epair,
                                                      const void* __restrict__ b2,
                                                      void* __restrict__ outp,
                                                      const int* __restrict__ flags) {
    int tid = threadIdx.x;
    int lane = tid & 63, wv = tid >> 6;
    int g = lane >> 3, l = lane & 7;   // group = dest, 8 feature-lanes
    int c = blockIdx.x * 32 + wv * 8 + g;
    if (c >= NN) return;
    int bf = flags[0];
    float dc = dinv[c];
    int jb = off[c], je = off[c + 1];
    float acc[8];
    {
        short8 v = *(const short8*)(h + (size_t)c * 64 + l * 8);
        float w = dc * dc;
#pragma unroll
        for (int f = 0; f < 8; ++f) acc[f] = bf2f((unsigned short)v[f]) * w;
    }
    int j = jb;
    for (; j + 3 < je; j += 4) {
        int s0 = epair[j], s1 = epair[j + 1], s2 = epair[j + 2], s3 = epair[j + 3];
        float w0 = dinv[s0] * dc, w1 = dinv[s1] * dc;
        float w2 = dinv[s2] * dc, w3 = dinv[s3] * dc;
        short8 v0 = *(const short8*)(h + (size_t)s0 * 64 + l * 8);
        short8 v1 = *(const short8*)(h + (size_t)s1 * 64 + l * 8);
        short8 v2 = *(const short8*)(h + (size_t)s2 * 64 + l * 8);
        short8 v3 = *(const short8*)(h + (size_t)s3 * 64 + l * 8);
#pragma unroll
        for (int f = 0; f < 8; ++f) {
            acc[f] = fmaf(bf2f((unsigned short)v0[f]), w0, acc[f]);
            acc[f] = fmaf(bf2f((unsigned short)v1[f]), w1, acc[f]);
            acc[f] = fmaf(bf2f((unsigned short)v2[f]), w2, acc[f]);
            acc[f] = fmaf(bf2f((unsigned short)v3[f]), w3, acc[f]);
        }
    }
    for (; j < je; ++j) {
        int s0 = epair[j];
        float w = dinv[s0] * dc;
        short8 v = *(const short8*)(h + (size_t)s0 * 64 + l * 8);
#pragma unroll
        for (int f = 0; f < 8; ++f) acc[f] = fmaf(bf2f((unsigned short)v[f]), w, acc[f]);
    }
    if (bf) {
        short8 o;
#pragma unroll
        for (int f = 0; f < 8; ++f)
            o[f] = (short)f2bf(acc[f] + ldf(b2, l * 8 + f, 1));
        *(short8*)((unsigned short*)outp + (size_t)c * 64 + l * 8) = o;
    } else {
        float* op = (float*)outp + (size_t)c * 64 + l * 8;
#pragma unroll
        for (int f = 0; f < 8; ++f)
            op[f] = acc[f] + ldf(b2, l * 8 + f, 0);
    }
}

extern "C" void kernel_launch(void* const* d_in, const int* in_sizes, int n_in,
                              void* d_out, int out_size, void* d_ws, size_t ws_size,
                              hipStream_t stream) {
    const void* x  = d_in[0];
    const void* ei = d_in[1];
    const void* W1 = d_in[2];
    const void* b1 = d_in[3];
    const void* W2 = d_in[4];
    const void* b2 = d_in[5];

    const int N = NN;
    const int E = in_sizes[1] / 2;
    const int PB = (E + CH - 1) / CH;                  // sort blocks
    const int GB = (N + 127) / 128;                    // gemm blocks (128 rows each)
    const int TB = (128 * 256 + 64 * 128 + 511) / 512; // transpose blocks

    char* ws = (char*)d_ws;
    size_t o = 0;
    auto alloc = [&](size_t bytes) { size_t r = o; o += (bytes + 255) & ~(size_t)255; return r; };
    int*   flags  = (int*)(ws + alloc(256));
    int*   bcnt   = (int*)(ws + alloc((size_t)(NB + 1) * 4));
    int*   off    = (int*)(ws + alloc((size_t)(N + 1) * 4));
    float* dinv   = (float*)(ws + alloc((size_t)N * 4));
    int*   epair  = (int*)(ws + alloc((size_t)E * 4));
    int*   poff   = (int*)(ws + alloc((size_t)PB * (NB + 1) * 4));
    unsigned short* w1t  = (unsigned short*)(ws + alloc(128 * 256 * 2));
    unsigned short* w2t  = (unsigned short*)(ws + alloc(64 * 128 * 2));
    unsigned short* h1   = (unsigned short*)(ws + alloc((size_t)N * 128 * 2));
    unsigned short* buf2 = (unsigned short*)(ws + alloc((size_t)N * 128 * 2));
    unsigned short* h2   = buf2;        // h2 lives in buf2 (h1 stays live during ag1)
    int* ebin = (int*)buf2;             // staging reuse: ebin dead before ag1 writes h2

    hipMemsetAsync(bcnt, 0, (size_t)(NB + 1) * 4, stream);
    sort_tr_kernel<<<PB + TB, 512, 0, stream>>>(ei, E, bcnt, poff, ebin, flags, x, W1, W2, w1t, w2t, PB);
    sg1_kernel<<<GB + NB, 512, 0, stream>>>(ebin, poff, bcnt, off, dinv, epair, flags, x, w1t, h1, GB, PB);
    ag1_kernel<<<(N + 15) / 16, 256, 0, stream>>>(h1, dinv, off, epair, b1, w2t, h2, flags);
    agg_out_kernel<<<(N + 31) / 32, 256, 0, stream>>>(h2, dinv, off, epair, b2, d_out, flags);
}